// Round 3
// baseline (5984.478 us; speedup 1.0000x reference)
//
#include <hip/hip_runtime.h>
#include <math.h>

// Problem constants (fixed by the reference)
#define NPTS 500000
#define NTILES 7813                  // ceil(500000/64)
#define TPB 4                        // tiles per block
#define GRID ((NTILES + TPB - 1) / TPB)
#define LDP 68                       // LDS row stride (floats) for 64-wide point-major tiles

// khs pre-scale: (1/sqrt(8)) * log2(e)  -> e = exp2(qp * khs2)
#define KSCALE (0.35355339059327373f * 1.4426950408889634f)

// ws layout (float offsets):
// [0,4096)      WqT[k][c] = Wq[c][k]
// [4096,8192)   WoT[c][c'] = Wo[c'][c]
// [8192,8704)   khs2[b][c] = (k@Wk.T + bk) * KSCALE
// [8704,9216)   vh[b][c]  = v@Wv.T + bv
// [9216,10240)  z as double[512]  (byte offset 36864, 8-aligned)

__global__ void prep_kernel(const float* __restrict__ kin, const float* __restrict__ vin,
                            const float* __restrict__ Wq, const float* __restrict__ Wk,
                            const float* __restrict__ bk, const float* __restrict__ Wv,
                            const float* __restrict__ bv, const float* __restrict__ Wo,
                            float* __restrict__ ws) {
    const int gid = blockIdx.x * 256 + threadIdx.x;
    float* WqT = ws;
    float* WoT = ws + 4096;
    float* khs = ws + 8192;
    float* vh  = ws + 8704;
    double* zg = (double*)(ws + 9216);
    for (int idx = gid; idx < 4096; idx += 8 * 256) {
        int a = idx >> 6, b = idx & 63;
        WqT[idx] = Wq[b * 64 + a];
        WoT[idx] = Wo[b * 64 + a];
    }
    for (int idx = gid; idx < 512; idx += 8 * 256) {
        int b = idx >> 6, c = idx & 63;
        float dk = 0.f, dv = 0.f;
        #pragma unroll 8
        for (int j = 0; j < 64; ++j) {
            dk = fmaf(kin[b * 64 + j], Wk[c * 64 + j], dk);
            dv = fmaf(vin[b * 64 + j], Wv[c * 64 + j], dv);
        }
        khs[idx] = (dk + bk[c]) * KSCALE;
        vh[idx]  = dv + bv[c];
        zg[idx]  = 0.0;
    }
}

// passA: e = exp((q@Wq.T + bq) * k_scaled[batch]) -> e_out (aliases d_out), z-accum (f64 global)
__global__ __launch_bounds__(256, 4) void passA_kernel(const float* __restrict__ q,
                                                       const int* __restrict__ batch,
                                                       const float* __restrict__ bq,
                                                       float* __restrict__ ws,
                                                       float* __restrict__ e_out) {
    __shared__ __align__(16) float qL[64 * LDP];   // qL[p][k], row stride 68
    __shared__ __align__(16) float wq[4096];       // WqT[k][c]
    __shared__ __align__(16) float khs_l[512];
    __shared__ __align__(16) float bq_l[64];
    __shared__ int bs[64];
    __shared__ __align__(16) float zred[256];

    const float* WqT   = ws;
    const float* khs_g = ws + 8192;
    double* zg = (double*)(ws + 9216);

    const int tid = threadIdx.x;
    const int tx = tid & 15, ty = tid >> 4;   // thread owns ch 4tx..4tx+3, pts 4ty..4ty+3

    for (int idx = tid; idx < 1024; idx += 256) ((float4*)wq)[idx] = ((const float4*)WqT)[idx];
    for (int idx = tid; idx < 128; idx += 256) ((float4*)khs_l)[idx] = ((const float4*)khs_g)[idx];
    if (tid < 64) bq_l[tid] = bq[tid];

    float zacc[4] = {0.f, 0.f, 0.f, 0.f};
    int cur_b = -1;

    // per-thread fp32 partials -> wave shuffle over ty -> LDS -> one f64 atomic/channel.
    // Called only under block-uniform conditions.
    auto flushz = [&](int b) {
        if (b < 0) return;
        float v0 = zacc[0], v1 = zacc[1], v2 = zacc[2], v3 = zacc[3];
        v0 += __shfl_xor(v0, 16); v0 += __shfl_xor(v0, 32);
        v1 += __shfl_xor(v1, 16); v1 += __shfl_xor(v1, 32);
        v2 += __shfl_xor(v2, 16); v2 += __shfl_xor(v2, 32);
        v3 += __shfl_xor(v3, 16); v3 += __shfl_xor(v3, 32);
        __syncthreads();                 // zred reuse guard
        if ((tid & 48) == 0) {
            int wv = tid >> 6;
            *(float4*)&zred[wv * 64 + 4 * tx] = make_float4(v0, v1, v2, v3);
        }
        __syncthreads();
        if (tid < 64) {
            float s = zred[tid] + zred[64 + tid] + zred[128 + tid] + zred[192 + tid];
            unsafeAtomicAdd(&zg[b * 64 + tid], (double)s);
        }
        zacc[0] = zacc[1] = zacc[2] = zacc[3] = 0.f;
    };

    const int t0 = blockIdx.x * TPB;
    const int t1 = (t0 + TPB < NTILES) ? (t0 + TPB) : NTILES;

    // prefetch tile t0 (4 float4 of q rows ty+16r, plus batch)
    float4 pre[4];
    int bpre = 0;
    {
        const int p0g = t0 * 64;
        #pragma unroll
        for (int r = 0; r < 4; ++r) {
            int gp = p0g + ty + r * 16;
            pre[r] = (gp < NPTS) ? ((const float4*)q)[gp * 16 + tx]
                                 : make_float4(0.f, 0.f, 0.f, 0.f);
        }
        if (tid < 64) {
            int gp = p0g + tid;
            bpre = batch[gp < NPTS ? gp : (NPTS - 1)];
        }
    }
    __syncthreads();

    float bqa[4];
    { float4 b4 = *(const float4*)&bq_l[4 * tx];
      bqa[0] = b4.x; bqa[1] = b4.y; bqa[2] = b4.z; bqa[3] = b4.w; }

    for (int t = t0; t < t1; ++t) {
        const int p0g = t * 64;
        // stage: direct b128 writes, point-major, zero conflicts
        #pragma unroll
        for (int r = 0; r < 4; ++r)
            *(float4*)&qL[(ty + r * 16) * LDP + 4 * tx] = pre[r];
        if (tid < 64) bs[tid] = bpre;
        __syncthreads();

        // prefetch tile t+1 while GEMM runs
        if (t + 1 < t1) {
            const int np0 = (t + 1) * 64;
            #pragma unroll
            for (int r = 0; r < 4; ++r) {
                int gp = np0 + ty + r * 16;
                pre[r] = (gp < NPTS) ? ((const float4*)q)[gp * 16 + tx]
                                     : make_float4(0.f, 0.f, 0.f, 0.f);
            }
            if (tid < 64) {
                int gp = np0 + tid;
                bpre = batch[gp < NPTS ? gp : (NPTS - 1)];
            }
        }

        const int b_lo = bs[0], b_hi = bs[63];
        const bool uni = (b_lo == b_hi);
        if (uni) {
            if (cur_b != b_lo) { flushz(cur_b); cur_b = b_lo; }
        } else {
            flushz(cur_b); cur_b = -1;
        }

        // GEMM1 (dot-form): qp[p][c] = sum_k q[p][k] * Wq[c][k]
        float acc[4][4] = {};
        #pragma unroll
        for (int kk = 0; kk < 16; ++kk) {
            float w[4][4], a[4][4];
            #pragma unroll
            for (int m = 0; m < 4; ++m) {
                float4 t4 = *(const float4*)&wq[(4 * kk + m) * 64 + 4 * tx];
                w[m][0] = t4.x; w[m][1] = t4.y; w[m][2] = t4.z; w[m][3] = t4.w;
            }
            #pragma unroll
            for (int i = 0; i < 4; ++i) {
                float4 t4 = *(const float4*)&qL[(4 * ty + i) * LDP + 4 * kk];
                a[i][0] = t4.x; a[i][1] = t4.y; a[i][2] = t4.z; a[i][3] = t4.w;
            }
            #pragma unroll
            for (int i = 0; i < 4; ++i)
                #pragma unroll
                for (int j = 0; j < 4; ++j)
                    acc[i][j] = fmaf(a[i][0], w[0][j],
                                fmaf(a[i][1], w[1][j],
                                fmaf(a[i][2], w[2][j],
                                fmaf(a[i][3], w[3][j], acc[i][j]))));
        }

        // e = exp2(qp * khs2); store to e_out; accumulate z
        float ev[4][4];
        #pragma unroll
        for (int i = 0; i < 4; ++i) {
            int pl = 4 * ty + i, gp = p0g + pl;
            int bi = bs[pl];
            float4 k4 = *(const float4*)&khs_l[bi * 64 + 4 * tx];
            float kh[4] = {k4.x, k4.y, k4.z, k4.w};
            bool valid = (gp < NPTS);
            #pragma unroll
            for (int j = 0; j < 4; ++j)
                ev[i][j] = valid ? exp2f((acc[i][j] + bqa[j]) * kh[j]) : 0.f;
            if (valid)
                ((float4*)e_out)[gp * 16 + tx] = make_float4(ev[i][0], ev[i][1], ev[i][2], ev[i][3]);
        }

        if (uni) {
            #pragma unroll
            for (int j = 0; j < 4; ++j)
                zacc[j] += (ev[0][j] + ev[1][j]) + (ev[2][j] + ev[3][j]);
        } else {
            // rare boundary tile (<=7 in the whole grid)
            #pragma unroll
            for (int i = 0; i < 4; ++i) {
                int pl = 4 * ty + i, gp = p0g + pl;
                int bi = bs[pl];
                if (gp < NPTS) {
                    #pragma unroll
                    for (int j = 0; j < 4; ++j)
                        unsafeAtomicAdd(&zg[bi * 64 + 4 * tx + j], (double)ev[i][j]);
                }
            }
        }
        __syncthreads();   // qL about to be restaged
    }
    flushz(cur_b);
}

// passB: out = (e * (vh/z)[batch]) @ Wo.T + bo ; e read from d_out, out written in place
__global__ __launch_bounds__(256, 4) void passB_kernel(const int* __restrict__ batch,
                                                       const float* __restrict__ bo,
                                                       const float* __restrict__ ws,
                                                       float* __restrict__ out) {
    __shared__ __align__(16) float tL[64 * LDP];   // t[p][c], row stride 68
    __shared__ __align__(16) float wo[4096];       // WoT[c][c']
    __shared__ __align__(16) float w_l[512];
    __shared__ __align__(16) float bo_l[64];

    const float* WoT  = ws + 4096;
    const float* vh_g = ws + 8704;
    const double* zg  = (const double*)(ws + 9216);

    const int tid = threadIdx.x;
    const int tx = tid & 15, ty = tid >> 4;

    for (int idx = tid; idx < 1024; idx += 256) ((float4*)wo)[idx] = ((const float4*)WoT)[idx];
    for (int idx = tid; idx < 512; idx += 256)
        w_l[idx] = (float)((double)vh_g[idx] / zg[idx]);
    if (tid < 64) bo_l[tid] = bo[tid];

    const int t0 = blockIdx.x * TPB;
    const int t1 = (t0 + TPB < NTILES) ? (t0 + TPB) : NTILES;

    // prefetch tile t0: e rows + per-row batch
    float4 epre[4];
    int bpre[4];
    {
        const int p0g = t0 * 64;
        #pragma unroll
        for (int r = 0; r < 4; ++r) {
            int gp = p0g + ty + r * 16;
            bool valid = (gp < NPTS);
            epre[r] = valid ? ((const float4*)out)[gp * 16 + tx]
                            : make_float4(0.f, 0.f, 0.f, 0.f);
            bpre[r] = valid ? batch[gp] : 0;
        }
    }
    __syncthreads();

    float boa[4];
    { float4 b4 = *(const float4*)&bo_l[4 * tx];
      boa[0] = b4.x; boa[1] = b4.y; boa[2] = b4.z; boa[3] = b4.w; }

    for (int t = t0; t < t1; ++t) {
        const int p0g = t * 64;
        // stage t = e * w[batch]: direct b128 writes, point-major
        #pragma unroll
        for (int r = 0; r < 4; ++r) {
            float4 wv = *(const float4*)&w_l[bpre[r] * 64 + 4 * tx];
            float4 tv = make_float4(epre[r].x * wv.x, epre[r].y * wv.y,
                                    epre[r].z * wv.z, epre[r].w * wv.w);
            *(float4*)&tL[(ty + r * 16) * LDP + 4 * tx] = tv;
        }
        __syncthreads();

        // prefetch tile t+1 (disjoint from this tile's out-writes)
        if (t + 1 < t1) {
            const int np0 = (t + 1) * 64;
            #pragma unroll
            for (int r = 0; r < 4; ++r) {
                int gp = np0 + ty + r * 16;
                bool valid = (gp < NPTS);
                epre[r] = valid ? ((const float4*)out)[gp * 16 + tx]
                                : make_float4(0.f, 0.f, 0.f, 0.f);
                bpre[r] = valid ? batch[gp] : 0;
            }
        }

        // GEMM2 (dot-form): out[p][c'] = sum_c t[p][c] * Wo[c'][c] + bo
        float acc[4][4] = {};
        #pragma unroll
        for (int cc = 0; cc < 16; ++cc) {
            float w[4][4], a[4][4];
            #pragma unroll
            for (int m = 0; m < 4; ++m) {
                float4 t4 = *(const float4*)&wo[(4 * cc + m) * 64 + 4 * tx];
                w[m][0] = t4.x; w[m][1] = t4.y; w[m][2] = t4.z; w[m][3] = t4.w;
            }
            #pragma unroll
            for (int i = 0; i < 4; ++i) {
                float4 t4 = *(const float4*)&tL[(4 * ty + i) * LDP + 4 * cc];
                a[i][0] = t4.x; a[i][1] = t4.y; a[i][2] = t4.z; a[i][3] = t4.w;
            }
            #pragma unroll
            for (int i = 0; i < 4; ++i)
                #pragma unroll
                for (int j = 0; j < 4; ++j)
                    acc[i][j] = fmaf(a[i][0], w[0][j],
                                fmaf(a[i][1], w[1][j],
                                fmaf(a[i][2], w[2][j],
                                fmaf(a[i][3], w[3][j], acc[i][j]))));
        }

        #pragma unroll
        for (int i = 0; i < 4; ++i) {
            int gp = p0g + 4 * ty + i;
            if (gp < NPTS) {
                float4 o = make_float4(acc[i][0] + boa[0], acc[i][1] + boa[1],
                                       acc[i][2] + boa[2], acc[i][3] + boa[3]);
                ((float4*)out)[gp * 16 + tx] = o;
            }
        }
        __syncthreads();
    }
}

extern "C" void kernel_launch(void* const* d_in, const int* in_sizes, int n_in,
                              void* d_out, int out_size, void* d_ws, size_t ws_size,
                              hipStream_t stream) {
    const float* q   = (const float*)d_in[0];
    const float* k   = (const float*)d_in[1];
    const float* v   = (const float*)d_in[2];
    const float* Wq  = (const float*)d_in[3];
    const float* bq  = (const float*)d_in[4];
    const float* Wk  = (const float*)d_in[5];
    const float* bk  = (const float*)d_in[6];
    const float* Wv  = (const float*)d_in[7];
    const float* bv  = (const float*)d_in[8];
    const float* Wo  = (const float*)d_in[9];
    const float* bo  = (const float*)d_in[10];
    const int*  batch = (const int*)d_in[11];
    float* out = (float*)d_out;
    float* ws  = (float*)d_ws;

    prep_kernel<<<8, 256, 0, stream>>>(k, v, Wq, Wk, bk, Wv, bv, Wo, ws);
    passA_kernel<<<GRID, 256, 0, stream>>>(q, batch, bq, ws, out);
    passB_kernel<<<GRID, 256, 0, stream>>>(batch, bo, ws, out);
}